// Round 4
// baseline (183.518 us; speedup 1.0000x reference)
//
#include <hip/hip_runtime.h>
#include <math.h>

// Round 4: single fused kernel + tiny memset (2 dispatches total).
//   Identity: sum(G) = ||sum_n Hn[n]||^2, trace(G) = N  =>  no N x N Gram.
//   Phase 1: per-block 128 KB panel (32 rows x 1024 cols) column sums-of-squares
//            -> atomicAdd norms2;  CE fused (1 logits row per thread t<32).
//   barrier (manual spin, 256 co-resident blocks)
//   Phase 2: SAME panel re-read (XCD-L2 hot): partial weighted row sums
//            s_vec[row] += dot(H_panel_row, rsqrt(norms2_slice)).
//   barrier
//   Phase 3: block 0: s2 = sum_d s_vec[d]^2; out = ce/B + (s2-N)*0.5/(N*(N-1)).
// Manual barrier is deadlock-safe: 256 blocks x 4 waves, ~16B LDS -> all blocks
// resident simultaneously regardless of packing.

#define N_COLS 8192
#define D_ROWS 1024
#define B_ROWS 8192
#define NBLK   256
#define EPSQ   1e-24f   // clamp on norms^2 (norms ~ 32 >> eps, this only dodges /0)

// ---------------------------------------------------------------------------
__device__ inline float block_reduce_sum_256(float v) {
    #pragma unroll
    for (int off = 32; off > 0; off >>= 1) v += __shfl_down(v, off, 64);
    __shared__ float sm[4];
    int lane = threadIdx.x & 63;
    int wid  = threadIdx.x >> 6;
    if (lane == 0) sm[wid] = v;
    __syncthreads();
    if (threadIdx.x < 4) {
        v = sm[threadIdx.x];
        v += __shfl_down(v, 2, 64);
        v += __shfl_down(v, 1, 64);
    }
    return v;
}

// ---------------------------------------------------------------------------
__global__ __launch_bounds__(256)
void fused_kernel(const float* __restrict__ H,
                  const float* __restrict__ logits,
                  const int* __restrict__ labels,
                  float* __restrict__ norms2,        // [N_COLS]
                  float* __restrict__ s_vec,         // [D_ROWS]
                  float* __restrict__ ce_acc,        // [1]
                  unsigned int* __restrict__ sync_ctr, // [2], pre-zeroed
                  float* __restrict__ out) {
    const int b = blockIdx.x, t = threadIdx.x;
    const int cg = b & 7;        // col-group: 1024 cols
    const int rg = b >> 3;       // row-group: 32 rows
    const int col4 = cg * 256 + t;                 // float4 column index
    const float4* __restrict__ H4 = (const float4*)H;

    // ---- Phase 1a: panel column sums of squares ----
    float ax = 0.f, ay = 0.f, az = 0.f, aw = 0.f;
    #pragma unroll 16
    for (int r = 0; r < 32; ++r) {
        float4 v = H4[(size_t)(rg * 32 + r) * (N_COLS / 4) + col4];
        ax = fmaf(v.x, v.x, ax);
        ay = fmaf(v.y, v.y, ay);
        az = fmaf(v.z, v.z, az);
        aw = fmaf(v.w, v.w, aw);
    }
    atomicAdd(&norms2[col4 * 4 + 0], ax);
    atomicAdd(&norms2[col4 * 4 + 1], ay);
    atomicAdd(&norms2[col4 * 4 + 2], az);
    atomicAdd(&norms2[col4 * 4 + 3], aw);

    // ---- Phase 1b: CE (rows b*32 .. b*32+31, one per thread t<32) ----
    float nll = 0.f;
    if (t < 32) {
        const int row = b * 32 + t;
        float2 x = ((const float2*)logits)[row];
        float m = fmaxf(x.x, x.y);
        float lse = m + __logf(__expf(x.x - m) + __expf(x.y - m));
        nll = lse - ((labels[row] == 0) ? x.x : x.y);
    }
    if (t < 64) {   // wave-0 reduce; lanes 32..63 carry 0
        #pragma unroll
        for (int off = 16; off > 0; off >>= 1) nll += __shfl_down(nll, off, 64);
        if (t == 0) atomicAdd(ce_acc, nll);
    }

    // ---- grid barrier #1 (all blocks proceed to phase 2) ----
    __threadfence();
    __syncthreads();
    if (t == 0) {
        atomicAdd(&sync_ctr[0], 1u);
        while (atomicAdd(&sync_ctr[0], 0u) < NBLK) __builtin_amdgcn_s_sleep(1);
    }
    __syncthreads();
    __threadfence();   // acquire: invalidate L1 so norms2 reads see L2

    // ---- Phase 2: weighted partial row sums over the SAME panel ----
    float4 n2 = ((const float4*)norms2)[col4];
    const float wx = rsqrtf(fmaxf(n2.x, EPSQ));
    const float wy = rsqrtf(fmaxf(n2.y, EPSQ));
    const float wz = rsqrtf(fmaxf(n2.z, EPSQ));
    const float ww = rsqrtf(fmaxf(n2.w, EPSQ));
    #pragma unroll 8
    for (int r = 0; r < 32; ++r) {
        float4 v = H4[(size_t)(rg * 32 + r) * (N_COLS / 4) + col4];
        float p = fmaf(v.x, wx, fmaf(v.y, wy, fmaf(v.z, wz, v.w * ww)));
        #pragma unroll
        for (int off = 32; off > 0; off >>= 1) p += __shfl_down(p, off, 64);
        if ((t & 63) == 0) atomicAdd(&s_vec[rg * 32 + r], p);
    }

    // ---- grid barrier #2 (only block 0 needs to wait) ----
    __threadfence();
    __syncthreads();
    if (t == 0) atomicAdd(&sync_ctr[1], 1u);
    if (b != 0) return;
    if (t == 0) {
        while (atomicAdd(&sync_ctr[1], 0u) < NBLK) __builtin_amdgcn_s_sleep(1);
    }
    __syncthreads();
    __threadfence();   // acquire before s_vec reads

    // ---- Phase 3: finalize on block 0 ----
    float sq = 0.f;
    #pragma unroll
    for (int i = 0; i < 4; ++i) {
        float s = s_vec[t + i * 256];
        sq = fmaf(s, s, sq);
    }
    float s2 = block_reduce_sum_256(sq);
    if (t == 0) {
        float ce = *(volatile float*)ce_acc;
        double reg = ((double)s2 - (double)N_COLS) * 0.5
                     / ((double)N_COLS * (double)(N_COLS - 1));
        out[0] = (float)((double)ce / (double)B_ROWS + reg);
    }
}

// ---------------------------------------------------------------------------
extern "C" void kernel_launch(void* const* d_in, const int* in_sizes, int n_in,
                              void* d_out, int out_size, void* d_ws, size_t ws_size,
                              hipStream_t stream) {
    const float* outputs = (const float*)d_in[0];   // [B, 2] f32
    const int*   labels  = (const int*)d_in[1];     // [B]
    const float* H       = (const float*)d_in[2];   // [D, N] f32
    float* out = (float*)d_out;

    // ws layout (floats): norms2[8192] | s_vec[1024] | ce_acc[1] | pad[7] | sync[2]
    float* norms2 = (float*)d_ws;
    float* s_vec  = norms2 + N_COLS;
    float* ce_acc = s_vec + D_ROWS;
    unsigned int* sync_ctr = (unsigned int*)(ce_acc + 8);

    const size_t zero_bytes = (N_COLS + D_ROWS + 8 + 2) * sizeof(float);
    hipMemsetAsync(d_ws, 0, zero_bytes, stream);

    fused_kernel<<<NBLK, 256, 0, stream>>>(H, outputs, labels,
                                           norms2, s_vec, ce_acc, sync_ctr, out);
}